// Round 7
// baseline (145.970 us; speedup 1.0000x reference)
//
#include <hip/hip_runtime.h>
#include <math.h>
#include <stdint.h>

#define B_ 4
#define S_ 1024
#define F_ 512    // W*DIM = HEADS*HD
#define HD 128
#define SOFT_C 4.0f   // fixed exp-centering; |S| << 88 so no running max needed

typedef __attribute__((ext_vector_type(8))) short short8;
typedef __attribute__((ext_vector_type(4))) float f32x4;
typedef __attribute__((ext_vector_type(4))) unsigned int u32x4;
typedef __attribute__((ext_vector_type(2))) unsigned int u32x2;

__device__ __forceinline__ unsigned short f2bf(float f) {
    unsigned int u = __float_as_uint(f);
    u = (u + 0x7FFFu + ((u >> 16) & 1u)) >> 16;
    return (unsigned short)u;
}
__device__ __forceinline__ float bf2f(unsigned int s) {
    return __uint_as_float(s << 16);
}
__device__ __forceinline__ void pack_hilo(const float* v, u32x4& hi, u32x4& lo) {
    #pragma unroll
    for (int p = 0; p < 4; ++p) {
        unsigned int h0 = f2bf(v[2 * p]), h1 = f2bf(v[2 * p + 1]);
        float l0 = v[2 * p] - bf2f(h0), l1 = v[2 * p + 1] - bf2f(h1);
        hi[p] = h0 | (h1 << 16);
        lo[p] = (unsigned int)f2bf(l0) | ((unsigned int)f2bf(l1) << 16);
    }
}

// ---------------------------------------------------------------------------
// K1 k_qkv: verbatim round-3/5 (verified 141 us).
// ---------------------------------------------------------------------------
__global__ __launch_bounds__(256) void k_qkv(
    const float* __restrict__ x, const int* __restrict__ embed_id,
    const float* __restrict__ qw, const float* __restrict__ kw,
    const float* __restrict__ vw,
    const float* __restrict__ strength, const float* __restrict__ str_w,
    const float* __restrict__ str_b,
    const float* __restrict__ pos, const float* __restrict__ pw1,
    const float* __restrict__ pb1, const float* __restrict__ pw2,
    const float* __restrict__ pb2, const float* __restrict__ head_w,
    unsigned short* __restrict__ yqh, unsigned short* __restrict__ ykh,
    unsigned short* __restrict__ yvt2,
    float* __restrict__ sv_g, float* __restrict__ xbar)
{
    __shared__ unsigned short whi[3][4096];   // fragment-major packed hi
    __shared__ unsigned short wlo[3][4096];   // fragment-major packed lo
    __shared__ float part_s[4][64];
    __shared__ float sv_s[64], svq_s[64];
    __shared__ float xr_s[4][8];
    __shared__ float red_s[4][4];
    __shared__ float inv_s[4];

    const int tid  = threadIdx.x;
    const int wv   = tid >> 6;
    const int lane = tid & 63;
    const int quad = lane >> 4;
    const int l15  = lane & 15;
    const float SCALE = 0.08838834764831845f;

    if (blockIdx.x >= 256) {
        // ---------------- xbar path with inline pos-softmax ----------------
        const int bi = blockIdx.x - 256;
        const int b = bi >> 6, c = bi & 63;
        float w1_[9], b1_[3], w2_[24], b2_[8], hw_[32];
        #pragma unroll
        for (int i = 0; i < 9; ++i)  w1_[i] = pw1[i];
        #pragma unroll
        for (int i = 0; i < 3; ++i)  b1_[i] = pb1[i];
        #pragma unroll
        for (int i = 0; i < 24; ++i) w2_[i] = pw2[i];
        #pragma unroll
        for (int i = 0; i < 8; ++i)  b2_[i] = pb2[i];
        #pragma unroll
        for (int i = 0; i < 32; ++i) hw_[i] = head_w[i];

        float pv_[4][4];
        float ps[4] = {0.f, 0.f, 0.f, 0.f};
        #pragma unroll
        for (int rr = 0; rr < 4; ++rr) {
            const int s = tid * 4 + rr;
            float p0 = pos[(b * S_ + s) * 3 + 0];
            float p1 = pos[(b * S_ + s) * 3 + 1];
            float p2 = pos[(b * S_ + s) * 3 + 2];
            float h0 = fmaxf(0.f, p0 * w1_[0] + p1 * w1_[1] + p2 * w1_[2] + b1_[0]);
            float h1 = fmaxf(0.f, p0 * w1_[3] + p1 * w1_[4] + p2 * w1_[5] + b1_[1]);
            float h2 = fmaxf(0.f, p0 * w1_[6] + p1 * w1_[7] + p2 * w1_[8] + b1_[2]);
            float ph[8];
            #pragma unroll
            for (int o8 = 0; o8 < 8; ++o8)
                ph[o8] = h0 * w2_[o8 * 3] + h1 * w2_[o8 * 3 + 1]
                       + h2 * w2_[o8 * 3 + 2] + b2_[o8];
            #pragma unroll
            for (int h = 0; h < 4; ++h) {
                float A = 0.f;
                #pragma unroll
                for (int o8 = 0; o8 < 8; ++o8) A += ph[o8] * hw_[h * 8 + o8];
                pv_[rr][h] = __expf(-A - 1.0f);
                ps[h] += pv_[rr][h];
            }
        }
        #pragma unroll
        for (int h = 0; h < 4; ++h)
            #pragma unroll
            for (int off = 1; off < 64; off <<= 1)
                ps[h] += __shfl_xor(ps[h], off);
        if (lane == 0)
            #pragma unroll
            for (int h = 0; h < 4; ++h) red_s[wv][h] = ps[h];
        __syncthreads();
        if (tid < 4)
            inv_s[tid] = 1.f / (red_s[0][tid] + red_s[1][tid]
                              + red_s[2][tid] + red_s[3][tid]);
        __syncthreads();

        const float* xc = x + (size_t)b * 524288 + c * 8192;
        float acc[8] = {};
        #pragma unroll
        for (int rr = 0; rr < 4; ++rr) {
            const int s = tid * 4 + rr;
            f32x4 x0 = *(const f32x4*)(xc + s * 8);
            f32x4 x1 = *(const f32x4*)(xc + s * 8 + 4);
            float q0 = pv_[rr][0] * inv_s[0];
            float q1 = pv_[rr][1] * inv_s[1];
            float q2 = pv_[rr][2] * inv_s[2];
            float q3 = pv_[rr][3] * inv_s[3];
            acc[0] += q0 * x0[0]; acc[1] += q0 * x0[1];
            acc[2] += q1 * x0[2]; acc[3] += q1 * x0[3];
            acc[4] += q2 * x1[0]; acc[5] += q2 * x1[1];
            acc[6] += q3 * x1[2]; acc[7] += q3 * x1[3];
        }
        #pragma unroll
        for (int j = 0; j < 8; ++j)
            #pragma unroll
            for (int off = 1; off < 64; off <<= 1)
                acc[j] += __shfl_xor(acc[j], off);
        if (lane == 0)
            #pragma unroll
            for (int j = 0; j < 8; ++j) xr_s[wv][j] = acc[j];
        __syncthreads();
        if (tid < 8)
            xbar[(b * 8 + tid) * 64 + c] = xr_s[0][tid] + xr_s[1][tid]
                                         + xr_s[2][tid] + xr_s[3][tid];
        return;
    }

    // ---------------- QKV path: stage packed weights + sv ----------------
    const int id = embed_id[0];

    for (int cc = tid; cc < 1536; cc += 256) {
        const int m  = cc >> 9;                 // wave-uniform per iter
        const int e0 = (cc & 511) << 3;
        const float* src = (m == 0 ? qw : m == 1 ? kw : vw) + id * 4096 + e0;
        const float sc = (m == 0) ? SCALE : 1.0f;
        f32x4 a0 = *(const f32x4*)src;
        f32x4 a1 = *(const f32x4*)(src + 4);
        float v8[8] = {a0[0] * sc, a0[1] * sc, a0[2] * sc, a0[3] * sc,
                       a1[0] * sc, a1[1] * sc, a1[2] * sc, a1[3] * sc};
        u32x4 hi, lo;
        pack_hilo(v8, hi, lo);
        const int r = e0 >> 6, c = e0 & 63;
        const int off = ((r >> 4) * 2 + (c >> 5)) * 512
                      + ((c >> 3) & 3) * 128 + (r & 15) * 8;
        *(u32x4*)(&whi[m][off]) = hi;
        *(u32x4*)(&wlo[m][off]) = lo;
    }

    {
        const float* wrow = str_w + lane * 512 + wv * 128;
        const float* st   = strength + wv * 128;
        float a = 0.f;
        #pragma unroll
        for (int j4 = 0; j4 < 32; ++j4) {
            f32x4 wv4 = *(const f32x4*)(wrow + j4 * 4);
            f32x4 s4  = *(const f32x4*)(st + j4 * 4);
            a += wv4[0] * s4[0] + wv4[1] * s4[1] + wv4[2] * s4[2] + wv4[3] * s4[3];
        }
        part_s[wv][lane] = a;
    }
    __syncthreads();
    if (tid < 64) {
        float v = part_s[0][tid] + part_s[1][tid] + part_s[2][tid]
                + part_s[3][tid] + str_b[tid];
        sv_s[tid]  = v;
        svq_s[tid] = v * SCALE;
        if (blockIdx.x == 0) sv_g[tid] = v;
    }
    __syncthreads();

    float svq_l[4], sv_l[4];
    #pragma unroll
    for (int nt = 0; nt < 4; ++nt) {
        svq_l[nt] = svq_s[nt * 16 + l15];
        sv_l[nt]  = sv_s[nt * 16 + l15];
    }
    f32x4 svA[4];
    #pragma unroll
    for (int mt = 0; mt < 4; ++mt)
        svA[mt] = *(const f32x4*)&sv_s[mt * 16 + quad * 4];

    #pragma unroll
    for (int u = 0; u < 2; ++u) {
        const int r0   = (blockIdx.x * 2 + u) * 64 + wv * 16;
        const int b    = r0 >> 13;
        const int rloc = (r0 & 8191) + l15;
        const float* xb = x + (size_t)b * 524288;

        u32x4 xhi[2], xlo[2];
        #pragma unroll
        for (int kc = 0; kc < 2; ++kc) {
            float xv[8];
            #pragma unroll
            for (int j = 0; j < 8; ++j)
                xv[j] = xb[(kc * 32 + quad * 8 + j) * 8192 + rloc];
            pack_hilo(xv, xhi[kc], xlo[kc]);
        }

        int idxq[4];
        #pragma unroll
        for (int rr = 0; rr < 4; ++rr) {
            const int rl = quad * 4 + rr;
            const int w_ = rl & 7;
            const int s_loc = ((r0 & 8191) >> 3) + (rl >> 3);
            idxq[rr] = (b * 4 + (w_ >> 1)) * 131072 + s_loc * 128 + (w_ & 1) * 64 + l15;
        }

        const int row_g = r0 + l15;
        const int s_idx = (row_g >> 3) & 1023;
        const int w_idx = row_g & 7;
        const int bh    = b * 4 + (w_idx >> 1);
        const int dbase = (w_idx & 1) * 64;
        unsigned short* vtb = yvt2 + (size_t)bh * 131072 + (s_idx >> 6) * 8192
                            + (size_t)dbase * 64 + (s_idx & 63);

        #pragma unroll
        for (int mat = 0; mat < 2; ++mat) {
            const unsigned short* mh = whi[mat];
            const unsigned short* ml = wlo[mat];
            f32x4 acc[4] = {};
            #pragma unroll
            for (int kc = 0; kc < 2; ++kc)
                #pragma unroll
                for (int nt = 0; nt < 4; ++nt) {
                    const int off = (nt * 2 + kc) * 512 + quad * 128 + l15 * 8;
                    u32x4 ehi = *(const u32x4*)(mh + off);
                    u32x4 elo = *(const u32x4*)(ml + off);
                    acc[nt] = __builtin_amdgcn_mfma_f32_16x16x32_bf16(
                        __builtin_bit_cast(short8, xhi[kc]),
                        __builtin_bit_cast(short8, ehi), acc[nt], 0, 0, 0);
                    acc[nt] = __builtin_amdgcn_mfma_f32_16x16x32_bf16(
                        __builtin_bit_cast(short8, xlo[kc]),
                        __builtin_bit_cast(short8, ehi), acc[nt], 0, 0, 0);
                    acc[nt] = __builtin_amdgcn_mfma_f32_16x16x32_bf16(
                        __builtin_bit_cast(short8, xhi[kc]),
                        __builtin_bit_cast(short8, elo), acc[nt], 0, 0, 0);
                }
            unsigned short* y = (mat == 0 ? yqh : ykh);
            const float* svp = (mat == 0 ? svq_l : sv_l);
            #pragma unroll
            for (int nt = 0; nt < 4; ++nt)
                #pragma unroll
                for (int rr = 0; rr < 4; ++rr)
                    y[(size_t)idxq[rr] + nt * 16] = f2bf(acc[nt][rr] + svp[nt]);
        }

        {
            const unsigned short* mh = whi[2];
            const unsigned short* ml = wlo[2];
            f32x4 acc[4] = {};
            #pragma unroll
            for (int kc = 0; kc < 2; ++kc)
                #pragma unroll
                for (int mt = 0; mt < 4; ++mt) {
                    const int off = (mt * 2 + kc) * 512 + quad * 128 + l15 * 8;
                    u32x4 ehi = *(const u32x4*)(mh + off);
                    u32x4 elo = *(const u32x4*)(ml + off);
                    acc[mt] = __builtin_amdgcn_mfma_f32_16x16x32_bf16(
                        __builtin_bit_cast(short8, ehi),
                        __builtin_bit_cast(short8, xhi[kc]), acc[mt], 0, 0, 0);
                    acc[mt] = __builtin_amdgcn_mfma_f32_16x16x32_bf16(
                        __builtin_bit_cast(short8, ehi),
                        __builtin_bit_cast(short8, xlo[kc]), acc[mt], 0, 0, 0);
                    acc[mt] = __builtin_amdgcn_mfma_f32_16x16x32_bf16(
                        __builtin_bit_cast(short8, elo),
                        __builtin_bit_cast(short8, xhi[kc]), acc[mt], 0, 0, 0);
                }
            #pragma unroll
            for (int mt = 0; mt < 4; ++mt)
                #pragma unroll
                for (int rr = 0; rr < 4; ++rr) {
                    const int c = mt * 16 + quad * 4 + rr;
                    vtb[(size_t)c * 64] = f2bf(acc[mt][rr] + svA[mt][rr]);
                }
        }
    }
}

// ---------------------------------------------------------------------------
// K2 k_attn: flash attention, 8-WAVE blocks (512 thr), wave = (qh, ts 16-t
// slice).  Same grid (512 blocks = 2/CU) -> 16 waves/CU = 4 waves/SIMD, 2x
// the TLP of r3, same per-block LDS traffic.  PV uses the PROVEN 16x16x32
// MFMA with the upper 16 k-slots zeroed (quads 2,3 carry B=0; their V reads
// are clamped in-bounds and contribute exactly zero).  Single-buffered LDS
// tile + register prefetch; 4-partial cross-wave reduction then the
// r3-verified epilogue on waves ts<2.
// ---------------------------------------------------------------------------
__global__ __launch_bounds__(512, 4) void k_attn(
    const unsigned short* __restrict__ yqh, const unsigned short* __restrict__ ykh,
    const unsigned short* __restrict__ yvt2,
    const float* __restrict__ xbar, const float* __restrict__ vw,
    const int* __restrict__ embed_id, const float* __restrict__ sv,
    const float* __restrict__ gate,
    const float* __restrict__ out_w, const float* __restrict__ out_b,
    float* __restrict__ out)
{
    // kx [64][136] shorts (17408 B) | vx [128][72] shorts (18432 B) | 16B pad
    // obuf (33792 B) aliases the arena after the loop.
    __shared__ __align__(16) unsigned char smem_kv[35856];
    __shared__ float vbar_s[128];
    __shared__ float vbarP_s[128];      // (vbar @ ow^T) per d-seg
    __shared__ float lsq_s[2][4][16];   // [qh][ts][q]

    unsigned short* kx = (unsigned short*)smem_kv;
    unsigned short* vx = (unsigned short*)(smem_kv + 17408);

    const int tid  = threadIdx.x;
    const int w    = tid >> 6;          // 0..7
    const int lane = tid & 63;
    const int quad = lane >> 4;
    const int l15  = lane & 15;
    const int bh = blockIdx.x & 15, qt = blockIdx.x >> 4;
    const int b = bh >> 2, h = bh & 3;
    const int s0 = qt * 32;
    const int qh = w >> 2;              // q-half (16 rows)
    const int ts = w & 3;               // 16-t slice of each 64-t tile

    const unsigned short* ykb = ykh + (size_t)bh * 131072;
    const unsigned short* yvb = yvt2 + (size_t)bh * 131072;

    // ---- vbar prologue (pos branch, rank-1 reconstruction) ----
    if (tid < 128) {
        const int c = tid & 63, wloc = tid >> 6;
        const float* ver = vw + embed_id[0] * 4096 + c * 64;
        const float* xbr = xbar + (b * 8 + h * 2 + wloc) * 64;
        float a = sv[c];
        #pragma unroll
        for (int j4 = 0; j4 < 16; ++j4) {
            f32x4 e4 = *(const f32x4*)(ver + j4 * 4);
            f32x4 x4 = *(const f32x4*)(xbr + j4 * 4);
            a += e4[0] * x4[0] + e4[1] * x4[1] + e4[2] * x4[2] + e4[3] * x4[3];
        }
        vbar_s[wloc * 64 + c] = a;
    }

    // ---- Q fragments: B[n=q(l15)][k=d(quad*8+j)], kc = 0..3 ----
    u32x4 qf[4];
    #pragma unroll
    for (int kc = 0; kc < 4; ++kc)
        qf[kc] = *(const u32x4*)(yqh + (size_t)bh * 131072
                 + (s0 + qh * 16 + l15) * 128 + kc * 32 + quad * 8);

    // ---- stage tile 0 (512 threads: 2 rows of 8 shorts each) ----
    #pragma unroll
    for (int r = 0; r < 2; ++r) {
        const int off = r * 4096 + tid * 8;
        *(u32x4*)&kx[(off >> 7) * 136 + (off & 127)] =
            *(const u32x4*)(ykb + off);
        *(u32x4*)&vx[(off >> 6) * 72 + (off & 63)] =
            *(const u32x4*)(yvb + off);
    }
    __syncthreads();

    // vbarP = vbar @ ow^T
    if (tid < 128) {
        const int seg = tid >> 6, dq = tid & 63;
        const float* wr = out_w + dq * 64;
        float a = 0.f;
        #pragma unroll
        for (int j4 = 0; j4 < 16; ++j4) {
            f32x4 w4 = *(const f32x4*)(wr + j4 * 4);
            f32x4 v4 = *(const f32x4*)&vbar_s[seg * 64 + j4 * 4];
            a += w4[0] * v4[0] + w4[1] * v4[1] + w4[2] * v4[2] + w4[3] * v4[3];
        }
        vbarP_s[seg * 64 + dq] = a;
    }

    f32x4 o[8] = {};
    float lsum = 0.f;
    const int srcA = ((quad & 1) << 5) + l15;
    const int vcol = ts * 16 + (quad & 1) * 8;   // clamped: quads 2,3 mirror 0,1 (B=0 there)

    for (int it = 0; it < 16; ++it) {
        u32x4 kst[2], vst[2];
        const bool pre = (it < 15);
        if (pre) {
            const unsigned short* ksrc = ykb + (it + 1) * 8192;
            const unsigned short* vsrc = yvb + (it + 1) * 8192;
            #pragma unroll
            for (int r = 0; r < 2; ++r)
                kst[r] = *(const u32x4*)(ksrc + r * 4096 + tid * 8);
            #pragma unroll
            for (int r = 0; r < 2; ++r)
                vst[r] = *(const u32x4*)(vsrc + r * 4096 + tid * 8);
        }

        // QK^T for this wave's 16-t slice (4 MFMA)
        f32x4 sa = {};
        #pragma unroll
        for (int kc = 0; kc < 4; ++kc) {
            u32x4 a0 = *(const u32x4*)&kx[(ts * 16 + l15) * 136 + kc * 32 + quad * 8];
            sa = __builtin_amdgcn_mfma_f32_16x16x32_bf16(
                __builtin_bit_cast(short8, a0),
                __builtin_bit_cast(short8, qf[kc]), sa, 0, 0, 0);
        }

        float p0[4];
        #pragma unroll
        for (int r = 0; r < 4; ++r) {
            p0[r] = __expf(sa[r] - SOFT_C);
            lsum += p0[r];
        }
        unsigned int pk00 = (unsigned int)f2bf(p0[0]) | ((unsigned int)f2bf(p0[1]) << 16);
        unsigned int pk01 = (unsigned int)f2bf(p0[2]) | ((unsigned int)f2bf(p0[3]) << 16);

        // P fragment for K=32 PV: k = quad*8+j; this wave's 16 t fill k=0..15
        // (source quads 0,1 for quad 0; quads 2,3 for quad 1); k=16..31 are 0.
        u32x4 pf;
        pf[0] = (unsigned int)__shfl((int)pk00, srcA);
        pf[1] = (unsigned int)__shfl((int)pk01, srcA);
        pf[2] = (unsigned int)__shfl((int)pk00, srcA + 16);
        pf[3] = (unsigned int)__shfl((int)pk01, srcA + 16);
        if (quad >= 2) { pf[0] = 0; pf[1] = 0; pf[2] = 0; pf[3] = 0; }

        #pragma unroll
        for (int dt = 0; dt < 8; ++dt) {
            u32x4 vf = *(const u32x4*)&vx[(dt * 16 + l15) * 72 + vcol];
            o[dt] = __builtin_amdgcn_mfma_f32_16x16x32_bf16(
                __builtin_bit_cast(short8, vf),
                __builtin_bit_cast(short8, pf), o[dt], 0, 0, 0);
        }

        __syncthreads();            // all waves done READING the tile
        if (pre) {
            #pragma unroll
            for (int r = 0; r < 2; ++r) {
                const int off = r * 4096 + tid * 8;
                *(u32x4*)&kx[(off >> 7) * 136 + (off & 127)] = kst[r];
            }
            #pragma unroll
            for (int r = 0; r < 2; ++r) {
                const int off = r * 4096 + tid * 8;
                *(u32x4*)&vx[(off >> 6) * 72 + (off & 63)] = vst[r];
            }
            __syncthreads();        // writes visible before next compute
        }
    }

    // ---- 4-partial cross-wave reduction through obuf (arena alias) ----
    float* obuf = (float*)smem_kv;
    if (ts >= 2) {
        float* ow_ = obuf + ((qh * 2 + (ts - 2)) * 16 + l15) * 132;
        #pragma unroll
        for (int dt = 0; dt < 8; ++dt)
            *(f32x4*)(ow_ + dt * 16 + quad * 4) = o[dt];
    }
    lsum += __shfl_xor(lsum, 16);
    lsum += __shfl_xor(lsum, 32);
    if (quad == 0) lsq_s[qh][ts][l15] = lsum;
    __syncthreads();
    if (ts < 2) {
        float* ow_ = obuf + ((qh * 2 + ts) * 16 + l15) * 132;
        #pragma unroll
        for (int dt = 0; dt < 8; ++dt) {
            f32x4 pr = *(const f32x4*)(ow_ + dt * 16 + quad * 4);
            o[dt] += pr;
            *(f32x4*)(ow_ + dt * 16 + quad * 4) = o[dt];
        }
    }
    __syncthreads();

    // ---- epilogue (waves ts<2 only; ts = d-seg), r3-verified structure ----
    if (ts < 2) {
        const float gf = 1.f / (1.f + __expf(-gate[h]));
        const float cf = (1.f - gf) / (lsq_s[qh][0][l15] + lsq_s[qh][1][l15]
                                     + lsq_s[qh][2][l15] + lsq_s[qh][3][l15]);
        const float* oa  = obuf + ((qh * 2 + 0) * 16 + l15) * 132;
        const float* obp = obuf + ((qh * 2 + 1) * 16 + l15) * 132;

        u32x4 bhi[2], blo[2];
        #pragma unroll
        for (int kc = 0; kc < 2; ++kc) {
            const int off = ts * 64 + kc * 32 + quad * 8;
            f32x4 a0 = *(const f32x4*)(oa + off);
            f32x4 a1 = *(const f32x4*)(oa + off + 4);
            f32x4 c0 = *(const f32x4*)(obp + off);
            f32x4 c1 = *(const f32x4*)(obp + off + 4);
            float yv[8] = {cf * (a0[0] + c0[0]), cf * (a0[1] + c0[1]),
                           cf * (a0[2] + c0[2]), cf * (a0[3] + c0[3]),
                           cf * (a1[0] + c1[0]), cf * (a1[1] + c1[1]),
                           cf * (a1[2] + c1[2]), cf * (a1[3] + c1[3])};
            pack_hilo(yv, bhi[kc], blo[kc]);
        }

        f32x4 acc[4] = {};
        #pragma unroll
        for (int kc = 0; kc < 2; ++kc)
            #pragma unroll
            for (int mt = 0; mt < 4; ++mt) {
                const float* wsrc2 = out_w + (mt * 16 + l15) * 64 + kc * 32 + quad * 8;
                f32x4 w0 = *(const f32x4*)wsrc2;
                f32x4 w1 = *(const f32x4*)(wsrc2 + 4);
                float wv8[8] = {w0[0], w0[1], w0[2], w0[3], w1[0], w1[1], w1[2], w1[3]};
                u32x4 ahi, alo;
                pack_hilo(wv8, ahi, alo);
                acc[mt] = __builtin_amdgcn_mfma_f32_16x16x32_bf16(
                    __builtin_bit_cast(short8, ahi),
                    __builtin_bit_cast(short8, bhi[kc]), acc[mt], 0, 0, 0);
                acc[mt] = __builtin_amdgcn_mfma_f32_16x16x32_bf16(
                    __builtin_bit_cast(short8, ahi),
                    __builtin_bit_cast(short8, blo[kc]), acc[mt], 0, 0, 0);
                acc[mt] = __builtin_amdgcn_mfma_f32_16x16x32_bf16(
                    __builtin_bit_cast(short8, alo),
                    __builtin_bit_cast(short8, bhi[kc]), acc[mt], 0, 0, 0);
            }

        const int w_seg = h * 2 + ts;
        const size_t rowb = ((size_t)(b * S_ + s0 + qh * 16 + l15) * 8 + w_seg) * 64;
        #pragma unroll
        for (int mt = 0; mt < 4; ++mt) {
            f32x4 vb   = *(const f32x4*)&vbarP_s[ts * 64 + mt * 16 + quad * 4];
            f32x4 bias = *(const f32x4*)(out_b + mt * 16 + quad * 4);
            f32x4 res;
            #pragma unroll
            for (int j = 0; j < 4; ++j) res[j] = acc[mt][j] + gf * vb[j] + bias[j];
            *(f32x4*)(out + rowb + mt * 16 + quad * 4) = res;
        }
    }
}

extern "C" void kernel_launch(void* const* d_in, const int* in_sizes, int n_in,
                              void* d_out, int out_size, void* d_ws, size_t ws_size,
                              hipStream_t stream) {
    (void)in_sizes; (void)n_in; (void)out_size; (void)ws_size;
    const float* x        = (const float*)d_in[0];
    const float* pos      = (const float*)d_in[1];
    const float* strength = (const float*)d_in[2];
    const int*   embed_id = (const int*)d_in[3];
    const float* qw       = (const float*)d_in[4];
    const float* kw       = (const float*)d_in[5];
    const float* vw       = (const float*)d_in[6];
    const float* pw1      = (const float*)d_in[7];
    const float* pb1      = (const float*)d_in[8];
    const float* pw2      = (const float*)d_in[9];
    const float* pb2      = (const float*)d_in[10];
    const float* head_w   = (const float*)d_in[11];
    const float* gate     = (const float*)d_in[13];
    const float* out_w    = (const float*)d_in[14];
    const float* out_b    = (const float*)d_in[15];
    const float* str_w    = (const float*)d_in[16];
    const float* str_b    = (const float*)d_in[17];
    float* out = (float*)d_out;

    unsigned short* yqh   = (unsigned short*)d_ws;         // 4 MiB
    unsigned short* ykh   = yqh + 2097152;                 // 4 MiB
    unsigned short* yvt2  = ykh + 2097152;                 // 4 MiB
    float* sv   = (float*)(yvt2 + 2097152);                // 64
    float* xbar = sv + 64;                                 // 2048

    k_qkv<<<512, 256, 0, stream>>>(x, embed_id, qw, kw, vw,
                                   strength, str_w, str_b,
                                   pos, pw1, pb1, pw2, pb2, head_w,
                                   yqh, ykh, yvt2, sv, xbar);
    k_attn<<<512, 512, 0, stream>>>(yqh, ykh, yvt2, xbar, vw, embed_id, sv,
                                    gate, out_w, out_b, out);
}

// Round 8
// 137.844 us; speedup vs baseline: 1.0590x; 1.0590x over previous
//
#include <hip/hip_runtime.h>
#include <math.h>
#include <stdint.h>

#define B_ 4
#define S_ 1024
#define F_ 512    // W*DIM = HEADS*HD
#define HD 128
#define SOFT_C 4.0f   // fixed exp-centering; |S| << 88 so no running max needed

typedef __attribute__((ext_vector_type(8))) short short8;
typedef __attribute__((ext_vector_type(4))) float f32x4;
typedef __attribute__((ext_vector_type(4))) unsigned int u32x4;
typedef __attribute__((ext_vector_type(2))) unsigned int u32x2;

__device__ __forceinline__ unsigned short f2bf(float f) {
    unsigned int u = __float_as_uint(f);
    u = (u + 0x7FFFu + ((u >> 16) & 1u)) >> 16;
    return (unsigned short)u;
}
__device__ __forceinline__ float bf2f(unsigned int s) {
    return __uint_as_float(s << 16);
}
__device__ __forceinline__ void pack_hilo(const float* v, u32x4& hi, u32x4& lo) {
    #pragma unroll
    for (int p = 0; p < 4; ++p) {
        unsigned int h0 = f2bf(v[2 * p]), h1 = f2bf(v[2 * p + 1]);
        float l0 = v[2 * p] - bf2f(h0), l1 = v[2 * p + 1] - bf2f(h1);
        hi[p] = h0 | (h1 << 16);
        lo[p] = (unsigned int)f2bf(l0) | ((unsigned int)f2bf(l1) << 16);
    }
}

// ---------------------------------------------------------------------------
// K1 k_qkv: verbatim round-3 (verified 141 us, 3x).
// ---------------------------------------------------------------------------
__global__ __launch_bounds__(256) void k_qkv(
    const float* __restrict__ x, const int* __restrict__ embed_id,
    const float* __restrict__ qw, const float* __restrict__ kw,
    const float* __restrict__ vw,
    const float* __restrict__ strength, const float* __restrict__ str_w,
    const float* __restrict__ str_b,
    const float* __restrict__ pos, const float* __restrict__ pw1,
    const float* __restrict__ pb1, const float* __restrict__ pw2,
    const float* __restrict__ pb2, const float* __restrict__ head_w,
    unsigned short* __restrict__ yqh, unsigned short* __restrict__ ykh,
    unsigned short* __restrict__ yvt2,
    float* __restrict__ sv_g, float* __restrict__ xbar)
{
    __shared__ unsigned short whi[3][4096];   // fragment-major packed hi
    __shared__ unsigned short wlo[3][4096];   // fragment-major packed lo
    __shared__ float part_s[4][64];
    __shared__ float sv_s[64], svq_s[64];
    __shared__ float xr_s[4][8];
    __shared__ float red_s[4][4];
    __shared__ float inv_s[4];

    const int tid  = threadIdx.x;
    const int wv   = tid >> 6;
    const int lane = tid & 63;
    const int quad = lane >> 4;
    const int l15  = lane & 15;
    const float SCALE = 0.08838834764831845f;

    if (blockIdx.x >= 256) {
        // ---------------- xbar path with inline pos-softmax ----------------
        const int bi = blockIdx.x - 256;
        const int b = bi >> 6, c = bi & 63;
        float w1_[9], b1_[3], w2_[24], b2_[8], hw_[32];
        #pragma unroll
        for (int i = 0; i < 9; ++i)  w1_[i] = pw1[i];
        #pragma unroll
        for (int i = 0; i < 3; ++i)  b1_[i] = pb1[i];
        #pragma unroll
        for (int i = 0; i < 24; ++i) w2_[i] = pw2[i];
        #pragma unroll
        for (int i = 0; i < 8; ++i)  b2_[i] = pb2[i];
        #pragma unroll
        for (int i = 0; i < 32; ++i) hw_[i] = head_w[i];

        float pv_[4][4];
        float ps[4] = {0.f, 0.f, 0.f, 0.f};
        #pragma unroll
        for (int rr = 0; rr < 4; ++rr) {
            const int s = tid * 4 + rr;
            float p0 = pos[(b * S_ + s) * 3 + 0];
            float p1 = pos[(b * S_ + s) * 3 + 1];
            float p2 = pos[(b * S_ + s) * 3 + 2];
            float h0 = fmaxf(0.f, p0 * w1_[0] + p1 * w1_[1] + p2 * w1_[2] + b1_[0]);
            float h1 = fmaxf(0.f, p0 * w1_[3] + p1 * w1_[4] + p2 * w1_[5] + b1_[1]);
            float h2 = fmaxf(0.f, p0 * w1_[6] + p1 * w1_[7] + p2 * w1_[8] + b1_[2]);
            float ph[8];
            #pragma unroll
            for (int o8 = 0; o8 < 8; ++o8)
                ph[o8] = h0 * w2_[o8 * 3] + h1 * w2_[o8 * 3 + 1]
                       + h2 * w2_[o8 * 3 + 2] + b2_[o8];
            #pragma unroll
            for (int h = 0; h < 4; ++h) {
                float A = 0.f;
                #pragma unroll
                for (int o8 = 0; o8 < 8; ++o8) A += ph[o8] * hw_[h * 8 + o8];
                pv_[rr][h] = __expf(-A - 1.0f);
                ps[h] += pv_[rr][h];
            }
        }
        #pragma unroll
        for (int h = 0; h < 4; ++h)
            #pragma unroll
            for (int off = 1; off < 64; off <<= 1)
                ps[h] += __shfl_xor(ps[h], off);
        if (lane == 0)
            #pragma unroll
            for (int h = 0; h < 4; ++h) red_s[wv][h] = ps[h];
        __syncthreads();
        if (tid < 4)
            inv_s[tid] = 1.f / (red_s[0][tid] + red_s[1][tid]
                              + red_s[2][tid] + red_s[3][tid]);
        __syncthreads();

        const float* xc = x + (size_t)b * 524288 + c * 8192;
        float acc[8] = {};
        #pragma unroll
        for (int rr = 0; rr < 4; ++rr) {
            const int s = tid * 4 + rr;
            f32x4 x0 = *(const f32x4*)(xc + s * 8);
            f32x4 x1 = *(const f32x4*)(xc + s * 8 + 4);
            float q0 = pv_[rr][0] * inv_s[0];
            float q1 = pv_[rr][1] * inv_s[1];
            float q2 = pv_[rr][2] * inv_s[2];
            float q3 = pv_[rr][3] * inv_s[3];
            acc[0] += q0 * x0[0]; acc[1] += q0 * x0[1];
            acc[2] += q1 * x0[2]; acc[3] += q1 * x0[3];
            acc[4] += q2 * x1[0]; acc[5] += q2 * x1[1];
            acc[6] += q3 * x1[2]; acc[7] += q3 * x1[3];
        }
        #pragma unroll
        for (int j = 0; j < 8; ++j)
            #pragma unroll
            for (int off = 1; off < 64; off <<= 1)
                acc[j] += __shfl_xor(acc[j], off);
        if (lane == 0)
            #pragma unroll
            for (int j = 0; j < 8; ++j) xr_s[wv][j] = acc[j];
        __syncthreads();
        if (tid < 8)
            xbar[(b * 8 + tid) * 64 + c] = xr_s[0][tid] + xr_s[1][tid]
                                         + xr_s[2][tid] + xr_s[3][tid];
        return;
    }

    // ---------------- QKV path: stage packed weights + sv ----------------
    const int id = embed_id[0];

    for (int cc = tid; cc < 1536; cc += 256) {
        const int m  = cc >> 9;                 // wave-uniform per iter
        const int e0 = (cc & 511) << 3;
        const float* src = (m == 0 ? qw : m == 1 ? kw : vw) + id * 4096 + e0;
        const float sc = (m == 0) ? SCALE : 1.0f;
        f32x4 a0 = *(const f32x4*)src;
        f32x4 a1 = *(const f32x4*)(src + 4);
        float v8[8] = {a0[0] * sc, a0[1] * sc, a0[2] * sc, a0[3] * sc,
                       a1[0] * sc, a1[1] * sc, a1[2] * sc, a1[3] * sc};
        u32x4 hi, lo;
        pack_hilo(v8, hi, lo);
        const int r = e0 >> 6, c = e0 & 63;
        const int off = ((r >> 4) * 2 + (c >> 5)) * 512
                      + ((c >> 3) & 3) * 128 + (r & 15) * 8;
        *(u32x4*)(&whi[m][off]) = hi;
        *(u32x4*)(&wlo[m][off]) = lo;
    }

    {
        const float* wrow = str_w + lane * 512 + wv * 128;
        const float* st   = strength + wv * 128;
        float a = 0.f;
        #pragma unroll
        for (int j4 = 0; j4 < 32; ++j4) {
            f32x4 wv4 = *(const f32x4*)(wrow + j4 * 4);
            f32x4 s4  = *(const f32x4*)(st + j4 * 4);
            a += wv4[0] * s4[0] + wv4[1] * s4[1] + wv4[2] * s4[2] + wv4[3] * s4[3];
        }
        part_s[wv][lane] = a;
    }
    __syncthreads();
    if (tid < 64) {
        float v = part_s[0][tid] + part_s[1][tid] + part_s[2][tid]
                + part_s[3][tid] + str_b[tid];
        sv_s[tid]  = v;
        svq_s[tid] = v * SCALE;
        if (blockIdx.x == 0) sv_g[tid] = v;
    }
    __syncthreads();

    float svq_l[4], sv_l[4];
    #pragma unroll
    for (int nt = 0; nt < 4; ++nt) {
        svq_l[nt] = svq_s[nt * 16 + l15];
        sv_l[nt]  = sv_s[nt * 16 + l15];
    }
    f32x4 svA[4];
    #pragma unroll
    for (int mt = 0; mt < 4; ++mt)
        svA[mt] = *(const f32x4*)&sv_s[mt * 16 + quad * 4];

    #pragma unroll
    for (int u = 0; u < 2; ++u) {
        const int r0   = (blockIdx.x * 2 + u) * 64 + wv * 16;
        const int b    = r0 >> 13;
        const int rloc = (r0 & 8191) + l15;
        const float* xb = x + (size_t)b * 524288;

        u32x4 xhi[2], xlo[2];
        #pragma unroll
        for (int kc = 0; kc < 2; ++kc) {
            float xv[8];
            #pragma unroll
            for (int j = 0; j < 8; ++j)
                xv[j] = xb[(kc * 32 + quad * 8 + j) * 8192 + rloc];
            pack_hilo(xv, xhi[kc], xlo[kc]);
        }

        int idxq[4];
        #pragma unroll
        for (int rr = 0; rr < 4; ++rr) {
            const int rl = quad * 4 + rr;
            const int w_ = rl & 7;
            const int s_loc = ((r0 & 8191) >> 3) + (rl >> 3);
            idxq[rr] = (b * 4 + (w_ >> 1)) * 131072 + s_loc * 128 + (w_ & 1) * 64 + l15;
        }

        const int row_g = r0 + l15;
        const int s_idx = (row_g >> 3) & 1023;
        const int w_idx = row_g & 7;
        const int bh    = b * 4 + (w_idx >> 1);
        const int dbase = (w_idx & 1) * 64;
        unsigned short* vtb = yvt2 + (size_t)bh * 131072 + (s_idx >> 6) * 8192
                            + (size_t)dbase * 64 + (s_idx & 63);

        #pragma unroll
        for (int mat = 0; mat < 2; ++mat) {
            const unsigned short* mh = whi[mat];
            const unsigned short* ml = wlo[mat];
            f32x4 acc[4] = {};
            #pragma unroll
            for (int kc = 0; kc < 2; ++kc)
                #pragma unroll
                for (int nt = 0; nt < 4; ++nt) {
                    const int off = (nt * 2 + kc) * 512 + quad * 128 + l15 * 8;
                    u32x4 ehi = *(const u32x4*)(mh + off);
                    u32x4 elo = *(const u32x4*)(ml + off);
                    acc[nt] = __builtin_amdgcn_mfma_f32_16x16x32_bf16(
                        __builtin_bit_cast(short8, xhi[kc]),
                        __builtin_bit_cast(short8, ehi), acc[nt], 0, 0, 0);
                    acc[nt] = __builtin_amdgcn_mfma_f32_16x16x32_bf16(
                        __builtin_bit_cast(short8, xlo[kc]),
                        __builtin_bit_cast(short8, ehi), acc[nt], 0, 0, 0);
                    acc[nt] = __builtin_amdgcn_mfma_f32_16x16x32_bf16(
                        __builtin_bit_cast(short8, xhi[kc]),
                        __builtin_bit_cast(short8, elo), acc[nt], 0, 0, 0);
                }
            unsigned short* y = (mat == 0 ? yqh : ykh);
            const float* svp = (mat == 0 ? svq_l : sv_l);
            #pragma unroll
            for (int nt = 0; nt < 4; ++nt)
                #pragma unroll
                for (int rr = 0; rr < 4; ++rr)
                    y[(size_t)idxq[rr] + nt * 16] = f2bf(acc[nt][rr] + svp[nt]);
        }

        {
            const unsigned short* mh = whi[2];
            const unsigned short* ml = wlo[2];
            f32x4 acc[4] = {};
            #pragma unroll
            for (int kc = 0; kc < 2; ++kc)
                #pragma unroll
                for (int mt = 0; mt < 4; ++mt) {
                    const int off = (mt * 2 + kc) * 512 + quad * 128 + l15 * 8;
                    u32x4 ehi = *(const u32x4*)(mh + off);
                    u32x4 elo = *(const u32x4*)(ml + off);
                    acc[mt] = __builtin_amdgcn_mfma_f32_16x16x32_bf16(
                        __builtin_bit_cast(short8, ehi),
                        __builtin_bit_cast(short8, xhi[kc]), acc[mt], 0, 0, 0);
                    acc[mt] = __builtin_amdgcn_mfma_f32_16x16x32_bf16(
                        __builtin_bit_cast(short8, ehi),
                        __builtin_bit_cast(short8, xlo[kc]), acc[mt], 0, 0, 0);
                    acc[mt] = __builtin_amdgcn_mfma_f32_16x16x32_bf16(
                        __builtin_bit_cast(short8, elo),
                        __builtin_bit_cast(short8, xhi[kc]), acc[mt], 0, 0, 0);
                }
            #pragma unroll
            for (int mt = 0; mt < 4; ++mt)
                #pragma unroll
                for (int rr = 0; rr < 4; ++rr) {
                    const int c = mt * 16 + quad * 4 + rr;
                    vtb[(size_t)c * 64] = f2bf(acc[mt][rr] + svA[mt][rr]);
                }
        }
    }
}

// ---------------------------------------------------------------------------
// K2 k_attn: r3's verified flash attention, TWO q-tiles per block sharing one
// K/V staging pass.  Block = 512 thr = two independent 4-wave groups; group
// g handles q-tile qt*64 + g*32 with the EXACT r3 wave geometry (wave =
// (qh, ts 32-t slice), shuffle P-transpose, full-d PV, fused oproj).  Grid
// 256 = 1 block/CU x 8 waves (same occupancy as r3); global K/V staging
// reads and LDS writes HALVE.  obuf = 8 partial sets (67.6 KB) aliasing the
// 71.7 KB kx/vx arena.
// ---------------------------------------------------------------------------
__global__ __launch_bounds__(512, 2) void k_attn(
    const unsigned short* __restrict__ yqh, const unsigned short* __restrict__ ykh,
    const unsigned short* __restrict__ yvt2,
    const float* __restrict__ xbar, const float* __restrict__ vw,
    const int* __restrict__ embed_id, const float* __restrict__ sv,
    const float* __restrict__ gate,
    const float* __restrict__ out_w, const float* __restrict__ out_b,
    float* __restrict__ out)
{
    // kx[2][64*136] shorts (34816 B) | vx[2][128*72] shorts (36864 B)
    // obuf 8 x [16][132] f32 (67584 B) aliases the arena after the loop.
    __shared__ __align__(16) unsigned char smem_kv[71680];
    __shared__ float vbar_s[128];
    __shared__ float vbarP_s[128];      // (vbar @ ow^T) per d-seg
    __shared__ float lsq_s[2][2][2][16];// [g][qh][ts][q]

    unsigned short* kxb = (unsigned short*)smem_kv;            // 2 x 8704
    unsigned short* vxb = (unsigned short*)(smem_kv + 34816);  // 2 x 9216

    const int tid  = threadIdx.x;
    const int w    = tid >> 6;          // 0..7
    const int lane = tid & 63;
    const int quad = lane >> 4;
    const int l15  = lane & 15;
    const int bh = blockIdx.x & 15, qt = blockIdx.x >> 4;   // qt 0..15
    const int b = bh >> 2, h = bh & 3;
    const int g  = w >> 2;              // q-tile group (0,1)
    const int wl = w & 3;               // wave within group
    const int qh = wl >> 1;             // q-half (16 rows)
    const int ts = wl & 1;              // t-slice (32 of 64) / d-seg epilogue
    const int s0 = qt * 64 + g * 32;    // this group's q-tile base

    const unsigned short* ykb = ykh + (size_t)bh * 131072;
    const unsigned short* yvb = yvt2 + (size_t)bh * 131072;

    // ---- vbar prologue (pos branch, rank-1 reconstruction; per-bh) ----
    if (tid < 128) {
        const int c = tid & 63, wloc = tid >> 6;
        const float* ver = vw + embed_id[0] * 4096 + c * 64;
        const float* xbr = xbar + (b * 8 + h * 2 + wloc) * 64;
        float a = sv[c];
        #pragma unroll
        for (int j4 = 0; j4 < 16; ++j4) {
            f32x4 e4 = *(const f32x4*)(ver + j4 * 4);
            f32x4 x4 = *(const f32x4*)(xbr + j4 * 4);
            a += e4[0] * x4[0] + e4[1] * x4[1] + e4[2] * x4[2] + e4[3] * x4[3];
        }
        vbar_s[wloc * 64 + c] = a;
    }

    // ---- Q fragments: B[n=q(l15)][k=d(quad*8+j)], kc = 0..3 ----
    u32x4 qf[4];
    #pragma unroll
    for (int kc = 0; kc < 4; ++kc)
        qf[kc] = *(const u32x4*)(yqh + (size_t)bh * 131072
                 + (s0 + qh * 16 + l15) * 128 + kc * 32 + quad * 8);

    // ---- stage tile 0 (512 threads: 2 chunks of 8 shorts each) ----
    #pragma unroll
    for (int r = 0; r < 2; ++r) {
        const int off = r * 4096 + tid * 8;
        *(u32x4*)&kxb[(off >> 7) * 136 + (off & 127)] =
            *(const u32x4*)(ykb + off);
        *(u32x4*)&vxb[(off >> 6) * 72 + (off & 63)] =
            *(const u32x4*)(yvb + off);
    }
    __syncthreads();

    // vbarP = vbar @ ow^T
    if (tid < 128) {
        const int seg = tid >> 6, dq = tid & 63;
        const float* wr = out_w + dq * 64;
        float a = 0.f;
        #pragma unroll
        for (int j4 = 0; j4 < 16; ++j4) {
            f32x4 w4 = *(const f32x4*)(wr + j4 * 4);
            f32x4 v4 = *(const f32x4*)&vbar_s[seg * 64 + j4 * 4];
            a += w4[0] * v4[0] + w4[1] * v4[1] + w4[2] * v4[2] + w4[3] * v4[3];
        }
        vbarP_s[seg * 64 + dq] = a;
    }

    f32x4 o[8] = {};
    float lsum = 0.f;
    const int srcA = ((quad & 1) << 5) + l15;

    for (int it = 0; it < 16; ++it) {
        const int cur = it & 1;
        u32x4 kst[2], vst[2];
        const bool pre = (it < 15);
        if (pre) {
            const unsigned short* ksrc = ykb + (it + 1) * 8192;
            const unsigned short* vsrc = yvb + (it + 1) * 8192;
            #pragma unroll
            for (int r = 0; r < 2; ++r)
                kst[r] = *(const u32x4*)(ksrc + r * 4096 + tid * 8);
            #pragma unroll
            for (int r = 0; r < 2; ++r)
                vst[r] = *(const u32x4*)(vsrc + r * 4096 + tid * 8);
        }

        const unsigned short* kxc = kxb + cur * 8704;
        const unsigned short* vxc = vxb + cur * 9216;

        // QK^T for this wave's 32-t slice (group-independent geometry)
        f32x4 sa0 = {}, sa1 = {};
        #pragma unroll
        for (int kc = 0; kc < 4; ++kc) {
            u32x4 a0 = *(const u32x4*)&kxc[(ts * 32 + l15) * 136 + kc * 32 + quad * 8];
            sa0 = __builtin_amdgcn_mfma_f32_16x16x32_bf16(
                __builtin_bit_cast(short8, a0),
                __builtin_bit_cast(short8, qf[kc]), sa0, 0, 0, 0);
        }
        #pragma unroll
        for (int kc = 0; kc < 4; ++kc) {
            u32x4 a1 = *(const u32x4*)&kxc[(ts * 32 + 16 + l15) * 136 + kc * 32 + quad * 8];
            sa1 = __builtin_amdgcn_mfma_f32_16x16x32_bf16(
                __builtin_bit_cast(short8, a1),
                __builtin_bit_cast(short8, qf[kc]), sa1, 0, 0, 0);
        }

        float p0[4], p1[4];
        #pragma unroll
        for (int r = 0; r < 4; ++r) {
            p0[r] = __expf(sa0[r] - SOFT_C);
            p1[r] = __expf(sa1[r] - SOFT_C);
            lsum += p0[r] + p1[r];
        }

        unsigned int pk00 = (unsigned int)f2bf(p0[0]) | ((unsigned int)f2bf(p0[1]) << 16);
        unsigned int pk01 = (unsigned int)f2bf(p0[2]) | ((unsigned int)f2bf(p0[3]) << 16);
        unsigned int pk10 = (unsigned int)f2bf(p1[0]) | ((unsigned int)f2bf(p1[1]) << 16);
        unsigned int pk11 = (unsigned int)f2bf(p1[2]) | ((unsigned int)f2bf(p1[3]) << 16);
        unsigned int sel0 = (quad < 2) ? pk00 : pk10;
        unsigned int sel1 = (quad < 2) ? pk01 : pk11;
        u32x4 pf;
        pf[0] = (unsigned int)__shfl((int)sel0, srcA);
        pf[1] = (unsigned int)__shfl((int)sel1, srcA);
        pf[2] = (unsigned int)__shfl((int)sel0, srcA + 16);
        pf[3] = (unsigned int)__shfl((int)sel1, srcA + 16);

        // PV over the FULL d=128 for this t-slice
        #pragma unroll
        for (int dt = 0; dt < 8; ++dt) {
            u32x4 vf = *(const u32x4*)&vxc[(dt * 16 + l15) * 72 + ts * 32 + quad * 8];
            o[dt] = __builtin_amdgcn_mfma_f32_16x16x32_bf16(
                __builtin_bit_cast(short8, vf),
                __builtin_bit_cast(short8, pf), o[dt], 0, 0, 0);
        }

        if (pre) {
            unsigned short* kxn = kxb + (cur ^ 1) * 8704;
            unsigned short* vxn = vxb + (cur ^ 1) * 9216;
            #pragma unroll
            for (int r = 0; r < 2; ++r) {
                const int off = r * 4096 + tid * 8;
                *(u32x4*)&kxn[(off >> 7) * 136 + (off & 127)] = kst[r];
            }
            #pragma unroll
            for (int r = 0; r < 2; ++r) {
                const int off = r * 4096 + tid * 8;
                *(u32x4*)&vxn[(off >> 6) * 72 + (off & 63)] = vst[r];
            }
        }
        __syncthreads();
    }

    // ---- cross-wave (ts) partial reduction: 8 sets in the arena ----
    // set index = g*4 + qh*2 + ts; row stride 132 (2-way alias, free)
    float* obuf = (float*)smem_kv;
    {
        float* ow_ = obuf + ((g * 4 + qh * 2 + ts) * 16 + l15) * 132;
        #pragma unroll
        for (int dt = 0; dt < 8; ++dt)
            *(f32x4*)(ow_ + dt * 16 + quad * 4) = o[dt];
    }
    lsum += __shfl_xor(lsum, 16);
    lsum += __shfl_xor(lsum, 32);
    if (quad == 0) lsq_s[g][qh][ts][l15] = lsum;
    __syncthreads();

    // ---- epilogue: sum partials, normalize, fused output projection ----
    const float gf = 1.f / (1.f + __expf(-gate[h]));
    const float cf = (1.f - gf) / (lsq_s[g][qh][0][l15] + lsq_s[g][qh][1][l15]);
    const float* oa  = obuf + ((g * 4 + qh * 2 + 0) * 16 + l15) * 132;
    const float* obp = obuf + ((g * 4 + qh * 2 + 1) * 16 + l15) * 132;

    // y B-fragments: B[k=din(kc*32+quad*8+j)][n=q(l15)], hi/lo split
    u32x4 bhi[2], blo[2];
    #pragma unroll
    for (int kc = 0; kc < 2; ++kc) {
        const int off = ts * 64 + kc * 32 + quad * 8;
        f32x4 a0 = *(const f32x4*)(oa + off);
        f32x4 a1 = *(const f32x4*)(oa + off + 4);
        f32x4 c0 = *(const f32x4*)(obp + off);
        f32x4 c1 = *(const f32x4*)(obp + off + 4);
        float yv[8] = {cf * (a0[0] + c0[0]), cf * (a0[1] + c0[1]),
                       cf * (a0[2] + c0[2]), cf * (a0[3] + c0[3]),
                       cf * (a1[0] + c1[0]), cf * (a1[1] + c1[1]),
                       cf * (a1[2] + c1[2]), cf * (a1[3] + c1[3])};
        pack_hilo(yv, bhi[kc], blo[kc]);
    }

    f32x4 acc[4] = {};
    #pragma unroll
    for (int kc = 0; kc < 2; ++kc)
        #pragma unroll
        for (int mt = 0; mt < 4; ++mt) {
            const float* wsrc2 = out_w + (mt * 16 + l15) * 64 + kc * 32 + quad * 8;
            f32x4 w0 = *(const f32x4*)wsrc2;
            f32x4 w1 = *(const f32x4*)(wsrc2 + 4);
            float wv8[8] = {w0[0], w0[1], w0[2], w0[3], w1[0], w1[1], w1[2], w1[3]};
            u32x4 ahi, alo;
            pack_hilo(wv8, ahi, alo);
            acc[mt] = __builtin_amdgcn_mfma_f32_16x16x32_bf16(
                __builtin_bit_cast(short8, ahi),
                __builtin_bit_cast(short8, bhi[kc]), acc[mt], 0, 0, 0);
            acc[mt] = __builtin_amdgcn_mfma_f32_16x16x32_bf16(
                __builtin_bit_cast(short8, ahi),
                __builtin_bit_cast(short8, blo[kc]), acc[mt], 0, 0, 0);
            acc[mt] = __builtin_amdgcn_mfma_f32_16x16x32_bf16(
                __builtin_bit_cast(short8, alo),
                __builtin_bit_cast(short8, bhi[kc]), acc[mt], 0, 0, 0);
        }

    const int w_seg = h * 2 + ts;
    const size_t rowb = ((size_t)(b * S_ + s0 + qh * 16 + l15) * 8 + w_seg) * 64;
    #pragma unroll
    for (int mt = 0; mt < 4; ++mt) {
        f32x4 vb   = *(const f32x4*)&vbarP_s[ts * 64 + mt * 16 + quad * 4];
        f32x4 bias = *(const f32x4*)(out_b + mt * 16 + quad * 4);
        f32x4 res;
        #pragma unroll
        for (int j = 0; j < 4; ++j) res[j] = acc[mt][j] + gf * vb[j] + bias[j];
        *(f32x4*)(out + rowb + mt * 16 + quad * 4) = res;
    }
}

extern "C" void kernel_launch(void* const* d_in, const int* in_sizes, int n_in,
                              void* d_out, int out_size, void* d_ws, size_t ws_size,
                              hipStream_t stream) {
    (void)in_sizes; (void)n_in; (void)out_size; (void)ws_size;
    const float* x        = (const float*)d_in[0];
    const float* pos      = (const float*)d_in[1];
    const float* strength = (const float*)d_in[2];
    const int*   embed_id = (const int*)d_in[3];
    const float* qw       = (const float*)d_in[4];
    const float* kw       = (const float*)d_in[5];
    const float* vw       = (const float*)d_in[6];
    const float* pw1      = (const float*)d_in[7];
    const float* pb1      = (const float*)d_in[8];
    const float* pw2      = (const float*)d_in[9];
    const float* pb2      = (const float*)d_in[10];
    const float* head_w   = (const float*)d_in[11];
    const float* gate     = (const float*)d_in[13];
    const float* out_w    = (const float*)d_in[14];
    const float* out_b    = (const float*)d_in[15];
    const float* str_w    = (const float*)d_in[16];
    const float* str_b    = (const float*)d_in[17];
    float* out = (float*)d_out;

    unsigned short* yqh   = (unsigned short*)d_ws;         // 4 MiB
    unsigned short* ykh   = yqh + 2097152;                 // 4 MiB
    unsigned short* yvt2  = ykh + 2097152;                 // 4 MiB
    float* sv   = (float*)(yvt2 + 2097152);                // 64
    float* xbar = sv + 64;                                 // 2048

    k_qkv<<<512, 256, 0, stream>>>(x, embed_id, qw, kw, vw,
                                   strength, str_w, str_b,
                                   pos, pw1, pb1, pw2, pb2, head_w,
                                   yqh, ykh, yvt2, sv, xbar);
    k_attn<<<256, 512, 0, stream>>>(yqh, ykh, yvt2, xbar, vw, embed_id, sv,
                                    gate, out_w, out_b, out);
}